// Round 3
// baseline (234.495 us; speedup 1.0000x reference)
//
#include <hip/hip_runtime.h>
#include <hip/hip_bf16.h>

#define SEQ 1024
#define DIM 128
#define NEG_SLOPE 0.1f

typedef __bf16 bf16x8 __attribute__((ext_vector_type(8)));
typedef float f32x4v __attribute__((ext_vector_type(4)));

// d_ws layout (bf16 elements):
//   [0, 32*128*1024)              nodes_t[b][d][o]
//   [NT, NT+16384)                Wt[d][k]   (W transposed)
//   [NT+16384, NT+32768)          Bt[d][k]   (B transposed)
#define NT_ELEMS (32u * 128u * 1024u)

__device__ __forceinline__ unsigned short bfb(float f) {
    __bf16 h = (__bf16)f;
    return __builtin_bit_cast(unsigned short, h);
}
__device__ __forceinline__ unsigned mpack(int x0, int x1) {
    unsigned m0 = (x0 != 0) ? 0x3F80u : 0u;   // bf16 1.0
    unsigned m1 = (x1 != 0) ? 0x3F80u : 0u;
    return m0 | (m1 << 16);
}

// ---- pre-kernel 1: nodes[b][o][d] f32 -> nodes_t[b][d][o] bf16 ----
// grid = 32 batches * 16 o-tiles(64) * 4 d-tiles(32) = 2048, block 256
__global__ __launch_bounds__(256)
void transpose_nodes(const float* __restrict__ nodes, unsigned short* __restrict__ nt)
{
    __shared__ float lds[64][33];
    const int bid = blockIdx.x;
    const int b   = bid >> 6;
    const int ot  = (bid >> 2) & 15;
    const int dt  = bid & 3;
    const int o0  = ot * 64, d0 = dt * 32;
    const int tid = threadIdx.x;

    const float* src = nodes + ((size_t)b * SEQ + o0) * DIM + d0;
    #pragma unroll
    for (int p = 0; p < 8; ++p) {
        const int o = (tid >> 5) + p * 8;
        const int d = tid & 31;
        lds[o][d] = src[(size_t)o * DIM + d];
    }
    __syncthreads();
    unsigned short* dst = nt + ((size_t)b * DIM + d0) * SEQ + o0;
    #pragma unroll
    for (int p = 0; p < 4; ++p) {
        const int d  = (tid >> 5) + p * 8;
        const int o2 = (tid & 31) * 2;
        ushort2 v;
        v.x = bfb(lds[o2][d]);
        v.y = bfb(lds[o2 + 1][d]);
        *(ushort2*)(dst + (size_t)d * SEQ + o2) = v;
    }
}

// ---- pre-kernel 2: W,B [k][d] f32 -> Wt,Bt [d][k] bf16 (64 KB total, L2-hot) ----
// grid = 32 (2 matrices x 16 slices), block 256
__global__ __launch_bounds__(256)
void transpose_wb(const float* __restrict__ W, const float* __restrict__ Bm,
                  unsigned short* __restrict__ wt, unsigned short* __restrict__ bt)
{
    const int which = blockIdx.x & 1;
    const int slice = blockIdx.x >> 1;             // 0..15, covers 1024 elems each
    const float* in  = which ? Bm : W;
    unsigned short* out = which ? bt : wt;
    const int base = slice * 1024;
    #pragma unroll
    for (int r = 0; r < 4; ++r) {
        const int idx = base + r * 256 + threadIdx.x;   // d*128 + k
        const int d = idx >> 7, k = idx & 127;
        out[idx] = bfb(in[k * DIM + d]);
    }
}

// ---- main fused kernel ----
// tile 64(i) x 128(d), grid 512 = 32 batch x 16 mtile, block 256 (2x2 waves)
union LdsU {
    unsigned short mask_t[2][64][72];   // [buf][i][o] bf16 bits (144B row, 16B aligned)
    unsigned short pooled[64][136];     // [i][d] bf16 bits (phase-2 A operand)
};

__global__ __launch_bounds__(256, 2)
void gcn_fused(const float* __restrict__ nodes,
               const int* __restrict__ adj,
               const unsigned short* __restrict__ nt,
               const unsigned short* __restrict__ wt,
               const unsigned short* __restrict__ bt,
               float* __restrict__ out)
{
    __shared__ LdsU u;

    const int bid   = blockIdx.x;
    const int xcd   = bid & 7;
    const int slot  = bid >> 3;
    const int batch = ((slot >> 4) << 3) | xcd;
    const int mtile = slot & 15;
    const int i0    = mtile << 6;

    const int tid  = threadIdx.x;
    const int wave = tid >> 6;
    const int lane = tid & 63;
    const int wm   = wave >> 1;
    const int wn   = wave & 1;
    const int lrow = lane & 15;
    const int quad = lane >> 4;

    const int*   __restrict__ adj_b   = adj   + (size_t)batch * SEQ * SEQ;
    const float* __restrict__ nodes_b = nodes + (size_t)batch * SEQ * DIM;
    const unsigned short* __restrict__ nt_b = nt + (size_t)batch * DIM * SEQ;

    // adj staging map: thread loads 4 rows (o) x int4 (4 i)
    const int a_row = (tid >> 4) * 4;
    const int a_col = (tid & 15) * 4;

    f32x4v acc[2][4] = {};
    f32x4v acc_cnt[2] = {};

    bf16x8 ones;
    #pragma unroll
    for (int j = 0; j < 8; ++j) ones[j] = __builtin_bit_cast(__bf16, (unsigned short)0x3F80);

    int4 A[4];
    auto load_adj = [&](int o0) {
        const int* pa = adj_b + (size_t)(o0 + a_row) * SEQ + (i0 + a_col);
        #pragma unroll
        for (int r = 0; r < 4; ++r) A[r] = *(const int4*)(pa + (size_t)r * SEQ);
    };

    const int d_b0 = wn * 64 + lrow;   // this wave's B-operand d base

    load_adj(0);

    for (int n = 0; n < 16; ++n) {
        const int buf = n & 1;
        // stage adj chunk n (transpose 4x4 in regs -> b64 LDS writes)
        #pragma unroll
        for (int j = 0; j < 4; ++j) {
            uint2 w;
            w.x = mpack(((const int*)&A[0])[j], ((const int*)&A[1])[j]);
            w.y = mpack(((const int*)&A[2])[j], ((const int*)&A[3])[j]);
            *(uint2*)&u.mask_t[buf][a_col + j][a_row] = w;
        }
        if (n < 15) load_adj((n + 1) * 64);   // keep HBM busy during MFMA
        __syncthreads();

        const int o_base = n * 64;
        #pragma unroll
        for (int kk = 0; kk < 2; ++kk) {
            const int ko = kk * 32 + quad * 8;
            bf16x8 av[2], bv[4];
            av[0] = *(const bf16x8*)&u.mask_t[buf][wm * 32 + lrow][ko];
            av[1] = *(const bf16x8*)&u.mask_t[buf][wm * 32 + 16 + lrow][ko];
            #pragma unroll
            for (int nf = 0; nf < 4; ++nf)
                bv[nf] = *(const bf16x8*)(nt_b + (size_t)(d_b0 + nf * 16) * SEQ + o_base + ko);
            #pragma unroll
            for (int mf = 0; mf < 2; ++mf) {
                #pragma unroll
                for (int nf = 0; nf < 4; ++nf)
                    acc[mf][nf] = __builtin_amdgcn_mfma_f32_16x16x32_bf16(av[mf], bv[nf], acc[mf][nf], 0, 0, 0);
                acc_cnt[mf] = __builtin_amdgcn_mfma_f32_16x16x32_bf16(av[mf], ones, acc_cnt[mf], 0, 0, 0);
            }
        }
    }

    // poolsum -> pooled (divide by MFMA-computed exact in-degree), C -> A layout via LDS
    __syncthreads();
    #pragma unroll
    for (int mf = 0; mf < 2; ++mf) {
        #pragma unroll
        for (int r = 0; r < 4; ++r) {
            const int row = wm * 32 + mf * 16 + quad * 4 + r;
            const float cnt = acc_cnt[mf][r];
            const float inv = (cnt > 0.5f) ? 1.0f / cnt : 0.0f;
            #pragma unroll
            for (int nf = 0; nf < 4; ++nf) {
                const int col = wn * 64 + nf * 16 + lrow;
                u.pooled[row][col] = bfb(acc[mf][nf][r] * inv);
            }
        }
    }
    __syncthreads();

    f32x4v acc2[2][4] = {};

    // pooled @ W + nodes @ B  (both K=128; Wt/Bt give 16B k-contiguous B-frags)
    #pragma unroll
    for (int ks = 0; ks < 4; ++ks) {
        const int k0 = ks * 32 + quad * 8;
        bf16x8 av[2], av2[2], bw[4], bb[4];
        #pragma unroll
        for (int mf = 0; mf < 2; ++mf) {
            av[mf] = *(const bf16x8*)&u.pooled[wm * 32 + mf * 16 + lrow][k0];
            const float* p = nodes_b + (size_t)(i0 + wm * 32 + mf * 16 + lrow) * DIM + k0;
            const float4 f1 = *(const float4*)p;
            const float4 f2 = *(const float4*)(p + 4);
            av2[mf][0] = (__bf16)f1.x; av2[mf][1] = (__bf16)f1.y;
            av2[mf][2] = (__bf16)f1.z; av2[mf][3] = (__bf16)f1.w;
            av2[mf][4] = (__bf16)f2.x; av2[mf][5] = (__bf16)f2.y;
            av2[mf][6] = (__bf16)f2.z; av2[mf][7] = (__bf16)f2.w;
        }
        #pragma unroll
        for (int nf = 0; nf < 4; ++nf) {
            bw[nf] = *(const bf16x8*)(wt + (size_t)(d_b0 + nf * 16) * DIM + k0);
            bb[nf] = *(const bf16x8*)(bt + (size_t)(d_b0 + nf * 16) * DIM + k0);
        }
        #pragma unroll
        for (int mf = 0; mf < 2; ++mf)
            #pragma unroll
            for (int nf = 0; nf < 4; ++nf) {
                acc2[mf][nf] = __builtin_amdgcn_mfma_f32_16x16x32_bf16(av[mf],  bw[nf], acc2[mf][nf], 0, 0, 0);
                acc2[mf][nf] = __builtin_amdgcn_mfma_f32_16x16x32_bf16(av2[mf], bb[nf], acc2[mf][nf], 0, 0, 0);
            }
    }

    // leaky-relu + store
    float* out_b = out + (size_t)batch * SEQ * DIM;
    #pragma unroll
    for (int mf = 0; mf < 2; ++mf) {
        #pragma unroll
        for (int nf = 0; nf < 4; ++nf) {
            const int col = wn * 64 + nf * 16 + lrow;
            #pragma unroll
            for (int r = 0; r < 4; ++r) {
                const int row = i0 + wm * 32 + mf * 16 + quad * 4 + r;
                const float x = acc2[mf][nf][r];
                out_b[(size_t)row * DIM + col] = (x > 0.0f) ? x : NEG_SLOPE * x;
            }
        }
    }
}

extern "C" void kernel_launch(void* const* d_in, const int* in_sizes, int n_in,
                              void* d_out, int out_size, void* d_ws, size_t ws_size,
                              hipStream_t stream) {
    const float* nodes = (const float*)d_in[0];
    const int*   adj   = (const int*)d_in[1];
    const float* W     = (const float*)d_in[2];
    const float* Bm    = (const float*)d_in[3];
    float*       out   = (float*)d_out;

    unsigned short* nt = (unsigned short*)d_ws;
    unsigned short* wt = nt + NT_ELEMS;
    unsigned short* bt = wt + 16384;

    transpose_nodes<<<dim3(2048), dim3(256), 0, stream>>>(nodes, nt);
    transpose_wb<<<dim3(32), dim3(256), 0, stream>>>(W, Bm, wt, bt);
    gcn_fused<<<dim3(512), dim3(256), 0, stream>>>(nodes, adj, nt, wt, bt, out);
}